// Round 11
// baseline (2509.963 us; speedup 1.0000x reference)
//
#include <hip/hip_runtime.h>
#include <stdint.h>

// PoseRNN: fused = cat(fv,fi) -> 2-layer GRU(768) -> Linear(768,128)+LeakyReLU(0.1) -> Linear(128,6)
// Persistent pipelined 2-layer GRU: 257 rounds, 192 WGs = 48 slices x 2 layers x 2 batch halves.
// Round-11 (on round-10 skeleton, single barrier, per-wave flags, fenceless protocol):
//   1. gh-GEMM K-split across the two gh waves with B-fragment sharing (each wave: both
//      16-row tiles, half of K): LDS B-reads halve -> on-chain GEMM leg ~35% shorter.
//      Partials in ghbuf[2][.]; combine sums. Single buffer (flag poll gates reuse).
//   2. Byte flags: one 128B line per (round,group); poll = 1-2 coalesced ubyte loads/lane.
//   3. Tight spin (no s_sleep) -> no 64cy poll quantization.
//   4. Fast sigmoid/tanh via __expf + clamp (libm tanhf is branchy).
// Derived from counters: effective clock ~1GHz (deep downclock from stalling); attack the
// serial legs, not occupancy.

typedef __attribute__((ext_vector_type(8))) short bf16x8;   // 8 bf16 in 4 VGPRs
typedef __attribute__((ext_vector_type(4))) short bf16x4;   // 8B
typedef __attribute__((ext_vector_type(4))) float f32x4;

#define H_   768
#define TH3  2304
#define BATCH 64
#define SEQ  256
#define SLAB (BATCH * H_)   /* 49152 elems, one timestep of h/y for all batches */
#define WROW 772            /* padded LDS row stride (ushorts) */
#define FB_ROUND 512        /* flag bytes per round: 4 groups x 128B (96 used per group) */

__device__ __forceinline__ uint16_t f2b(float f) {
  union { float f; uint32_t u; } v; v.f = f;
  uint32_t u = v.u;
  return (uint16_t)((u + 0x7FFFu + ((u >> 16) & 1u)) >> 16);  // RNE
}

__device__ __forceinline__ f32x4 mfma16(bf16x8 a, bf16x8 b, f32x4 c) {
  return __builtin_amdgcn_mfma_f32_16x16x32_bf16(a, b, c, 0, 0, 0);
}

__device__ __forceinline__ bf16x8 ldB(const uint16_t* p) {   // two ds_read_b64 (8B-aligned rows)
  bf16x4 lo = *reinterpret_cast<const bf16x4*>(p);
  bf16x4 hi = *reinterpret_cast<const bf16x4*>(p + 4);
  bf16x8 r;
  r[0] = lo[0]; r[1] = lo[1]; r[2] = lo[2]; r[3] = lo[3];
  r[4] = hi[0]; r[5] = hi[1]; r[6] = hi[2]; r[7] = hi[3];
  return r;
}

// flag byte layout: fb[(i*4+grp)*128 + m*48 + slice]
__device__ __forceinline__ size_t fbIdx(int i, int grp) { return ((size_t)i * 4 + grp) * 128; }

__device__ __forceinline__ uint8_t ldFlag(const uint8_t* p) {
  return __hip_atomic_load(p, __ATOMIC_RELAXED, __HIP_MEMORY_SCOPE_AGENT);
}

// poll all 96 bytes (both mblks x 48 slices) of one group-round record
__device__ __forceinline__ void pollFlags96(const uint8_t* base, int lane) {
  const uint8_t* p0 = base + lane;                 // bytes 0..63
  const uint8_t* p1 = base + 64 + (lane & 31);     // bytes 64..95 (lanes 0..31)
  int spins = 0;
  for (;;) {
    uint8_t a = ldFlag(p0);
    uint8_t b = (lane < 32) ? ldFlag(p1) : (uint8_t)1;
    if (__all(a && b)) break;
    if (++spins > (1 << 18)) break;  // hang guard; break => absmax fail, not timeout
  }
  __builtin_amdgcn_sched_barrier(0);  // nothing (esp. A-loads) may hoist above the poll
}

// poll 48 bytes (one mblk's slices)
__device__ __forceinline__ void pollFlags48(const uint8_t* base, int lane) {
  const uint8_t* p0 = base + (lane < 48 ? lane : 0);
  int spins = 0;
  for (;;) {
    uint8_t a = (lane < 48) ? ldFlag(p0) : (uint8_t)1;
    if (__all(a)) break;
    if (++spins > (1 << 18)) break;
  }
  __builtin_amdgcn_sched_barrier(0);
}

__device__ __forceinline__ float fsig(float x) {
  return 1.0f / (1.0f + __expf(-x));
}
__device__ __forceinline__ float ftanh(float x) {
  x = fminf(fmaxf(x, -15.0f), 15.0f);
  float e = __expf(2.0f * x);
  return (e - 1.0f) / (e + 1.0f);
}

// ---------------- prep: build time-major bf16 X, zero flags, bf16 W1 -------------
__global__ __launch_bounds__(256) void prep_kernel(
    const float* __restrict__ fv, const float* __restrict__ fi,
    const float* __restrict__ W1,
    uint16_t* __restrict__ Xbf, int* __restrict__ flags, uint16_t* __restrict__ W1b)
{
  const int NX = SEQ * SLAB;               // 12,582,912
  const int NC = 257 * FB_ROUND / 4;       // flag bytes as ints: 32,896
  const int NW = 128 * H_;
  const int total = NX + NC + NW;
  for (int idx = blockIdx.x * blockDim.x + threadIdx.x; idx < total;
       idx += gridDim.x * blockDim.x) {
    if (idx < NX) {
      int s = idx / SLAB;
      int rem = idx - s * SLAB;
      int b = rem / H_;
      int h = rem - b * H_;
      float val = (h < 512) ? fv[((size_t)b * SEQ + s) * 512 + h]
                            : fi[((size_t)b * SEQ + s) * 256 + (h - 512)];
      Xbf[idx] = f2b(val);
    } else if (idx < NX + NC) {
      flags[idx - NX] = 0;
    } else {
      int k = idx - NX - NC;
      W1b[k] = f2b(W1[k]);
    }
  }
}

// ---------------- persistent pipelined 2-layer GRU ----------------
__global__ __launch_bounds__(256) void gru_persist(
    const float* __restrict__ Wih, const float* __restrict__ Whh,
    const float* __restrict__ bih, const float* __restrict__ bhh,
    const uint16_t* __restrict__ Xbf, uint16_t* __restrict__ Y0, uint16_t* __restrict__ Y1,
    uint8_t* __restrict__ fbytes, float* __restrict__ out_hn)
{
  __shared__ __attribute__((aligned(16))) uint16_t Wx[48 * WROW];  // 74,112 B
  __shared__ __attribute__((aligned(16))) uint16_t Wh[48 * WROW];  // 74,112 B
  __shared__ float ghbuf[2 * 32 * 48];                             // 12,288 B (K-half partials)
  __shared__ float hmast[32 * 16];                                 //  2,048 B
  __shared__ float bI[48];
  __shared__ float bH[48];                                         // total 162,944 B

  const int bid   = blockIdx.x;        // 0..191
  const int slice = bid % 48;          // hidden slice: units [slice*16, slice*16+16)
  const int layer = (bid / 48) & 1;    // 0 or 1
  const int bhalf = bid / 96;          // batch half
  const int grp   = bhalf * 2 + layer; // flag group 0..3
  const int tid  = threadIdx.x;
  const int lane = tid & 63;
  const int wid  = tid >> 6;           // 4 waves
  const int isGh = wid >> 1;           // waves 0,1 -> x-GEMM+combine; waves 2,3 -> h-GEMM
  const int mblk = wid & 1;            // x-waves: batch sub-block
  const int kh   = wid & 1;            // gh-waves: K half (0: k<384, 1: k>=384)
  const int n16  = lane & 15;
  const int kg   = lane >> 4;

  // --- one-time: weight slices -> LDS bf16; rows ordered [r(16) z(16) n(16)] ---
  const float* wx_g = Wih + (size_t)layer * TH3 * H_;
  const float* wh_g = Whh + (size_t)layer * TH3 * H_;
  for (int idx = tid; idx < 48 * H_; idx += 256) {
    int lr = idx / H_;
    int c  = idx - lr * H_;
    int gate = lr >> 4, j = lr & 15;
    size_t grow = (size_t)(gate * H_ + slice * 16 + j);
    Wx[lr * WROW + c] = f2b(wx_g[grow * H_ + c]);
    Wh[lr * WROW + c] = f2b(wh_g[grow * H_ + c]);
  }
  if (tid < 48) {
    int gate = tid >> 4, j = tid & 15;
    bI[tid] = bih[layer * TH3 + gate * H_ + slice * 16 + j];
    bH[tid] = bhh[layer * TH3 + gate * H_ + slice * 16 + j];
  }
  for (int idx = tid; idx < 32 * 16; idx += 256) hmast[idx] = 0.0f;
  __syncthreads();

  const int batch0 = bhalf * 32;
  uint16_t* Yown = layer ? Y1 : Y0;
  const uint16_t* Wh_base = Wh + (size_t)n16 * WROW + kg * 8 + kh * 384;  // gh-wave B base
  const uint16_t* Wx_base = Wx + (size_t)n16 * WROW + kg * 8;             // x-wave B base

  f32x4 xac0 = {0,0,0,0}, xac1 = {0,0,0,0}, xac2 = {0,0,0,0};  // x-wave acc, live across barrier

  for (int i = 0; i <= 256; ++i) {
    const bool active = (layer == 0) ? (i < 256) : (i >= 1);
    const bool firstA = (layer == 0) ? (i == 0) : (i == 1);
    float* gb = ghbuf + kh * 1536;

    // ================= PRE-barrier =================
    if (active) {
      if (isGh) {
        if (firstA) {
          // h0 == 0 -> gh partials are 0; no poll, no GEMM
          #pragma unroll
          for (int q = 0; q < 4; ++q) {
            #pragma unroll
            for (int m = 0; m < 2; ++m) {
              int bi = m * 16 + 4 * kg + q;
              gb[bi * 48 +      n16] = 0.0f;
              gb[bi * 48 + 16 + n16] = 0.0f;
              gb[bi * 48 + 32 + n16] = 0.0f;
            }
          }
        } else {
          // wait for BOTH mblk producers of round i-1 (we read all 32 rows)
          pollFlags96(fbytes + fbIdx(i - 1, grp), lane);
          const uint16_t* hs = (layer == 0) ? (Y0 + (size_t)i * SLAB)
                                            : (Y1 + (size_t)(i - 1) * SLAB);
          const uint16_t* ap0 = hs + (size_t)(batch0 + n16) * H_ + kh * 384 + kg * 8;
          const uint16_t* ap1 = ap0 + (size_t)16 * H_;
          f32x4 a00 = {0,0,0,0}, a01 = {0,0,0,0}, a02 = {0,0,0,0};
          f32x4 a10 = {0,0,0,0}, a11 = {0,0,0,0}, a12 = {0,0,0,0};
          // K-half GEMM, B-fragments shared across the two 16-row tiles
          #pragma unroll
          for (int ks = 0; ks < 12; ++ks) {
            bf16x8 av0 = *reinterpret_cast<const bf16x8*>(ap0 + ks * 32);
            bf16x8 av1 = *reinterpret_cast<const bf16x8*>(ap1 + ks * 32);
            bf16x8 bv0 = ldB(Wh_base + ks * 32);
            bf16x8 bv1 = ldB(Wh_base + 16 * WROW + ks * 32);
            bf16x8 bv2 = ldB(Wh_base + 32 * WROW + ks * 32);
            a00 = mfma16(av0, bv0, a00);
            a01 = mfma16(av0, bv1, a01);
            a02 = mfma16(av0, bv2, a02);
            a10 = mfma16(av1, bv0, a10);
            a11 = mfma16(av1, bv1, a11);
            a12 = mfma16(av1, bv2, a12);
          }
          #pragma unroll
          for (int q = 0; q < 4; ++q) {
            int bi0 = 4 * kg + q;                    // D row = 4*(lane>>4)+q
            gb[bi0 * 48 +      n16] = a00[q];
            gb[bi0 * 48 + 16 + n16] = a01[q];
            gb[bi0 * 48 + 32 + n16] = a02[q];
            int bi1 = 16 + bi0;
            gb[bi1 * 48 +      n16] = a10[q];
            gb[bi1 * 48 + 16 + n16] = a11[q];
            gb[bi1 * 48 + 32 + n16] = a12[q];
          }
        }
      } else {
        // x input: layer0 reads Xbf[i] (static, no poll); layer1 reads Y0[i] (layer0 flags i-1)
        if (layer == 1) pollFlags48(fbytes + fbIdx(i - 1, bhalf * 2) + mblk * 48, lane);
        const uint16_t* xs = (layer == 0) ? (Xbf + (size_t)i * SLAB)
                                          : (Y0 + (size_t)i * SLAB);
        const uint16_t* ap = xs + (size_t)(batch0 + mblk * 16 + n16) * H_ + kg * 8;
        f32x4 a0 = {0,0,0,0}, a1 = {0,0,0,0}, a2 = {0,0,0,0};
        #pragma unroll
        for (int ks = 0; ks < 24; ++ks) {
          bf16x8 av  = *reinterpret_cast<const bf16x8*>(ap + ks * 32);
          bf16x8 bv0 = ldB(Wx_base + ks * 32);
          bf16x8 bv1 = ldB(Wx_base + 16 * WROW + ks * 32);
          bf16x8 bv2 = ldB(Wx_base + 32 * WROW + ks * 32);
          a0 = mfma16(av, bv0, a0);
          a1 = mfma16(av, bv1, a1);
          a2 = mfma16(av, bv2, a2);
        }
        xac0 = a0; xac1 = a1; xac2 = a2;
      }
    }

    __syncthreads();   // single barrier per round: ghbuf partials + xacc ready

    // ================= POST-barrier: x waves finish round i =================
    if (active && !isGh) {
      uint16_t* dst = Yown + (size_t)((layer == 0) ? (i + 1) : i) * SLAB;
      const bool lastStep = (layer == 0) ? (i == 255) : (i == 256);
      #pragma unroll
      for (int q = 0; q < 4; ++q) {
        int bi = mblk * 16 + 4 * kg + q;
        float ghr = ghbuf[bi * 48 +      n16] + ghbuf[1536 + bi * 48 +      n16] + bH[n16];
        float ghz = ghbuf[bi * 48 + 16 + n16] + ghbuf[1536 + bi * 48 + 16 + n16] + bH[16 + n16];
        float ghn = ghbuf[bi * 48 + 32 + n16] + ghbuf[1536 + bi * 48 + 32 + n16] + bH[32 + n16];
        float gxr = xac0[q] + bI[n16];
        float gxz = xac1[q] + bI[16 + n16];
        float gxn = xac2[q] + bI[32 + n16];
        float rg = fsig(gxr + ghr);
        float zg = fsig(gxz + ghz);
        float ng = ftanh(gxn + rg * ghn);
        float hv = hmast[bi * 16 + n16];
        float hn2 = (1.0f - zg) * ng + zg * hv;
        hmast[bi * 16 + n16] = hn2;
        // write-through (agent, relaxed) packed dword store: no dirty L2, no fences
        uint32_t lo = (uint32_t)f2b(hn2);
        uint32_t partner = (uint32_t)__shfl_xor((int)lo, 1, 64);  // col n16^1's bf16 bits
        if ((n16 & 1) == 0) {
          uint32_t pack = lo | (partner << 16);   // little-endian: col n16 low, n16+1 high
          uint32_t* p = (uint32_t*)(dst + (size_t)(batch0 + bi) * H_ + slice * 16 + n16);
          __hip_atomic_store(p, pack, __ATOMIC_RELAXED, __HIP_MEMORY_SCOPE_AGENT);
        }
        if (lastStep)
          out_hn[(size_t)layer * SLAB + (size_t)(batch0 + bi) * H_ + slice * 16 + n16] = hn2;
      }
      __builtin_amdgcn_s_waitcnt(0);      // drain THIS wave's h-stores (per-wave flag!)
      __builtin_amdgcn_sched_barrier(0);  // flag store must not move above the drain
      if (lane == 0)
        __hip_atomic_store(fbytes + fbIdx(i, grp) + mblk * 48 + slice, (uint8_t)1,
                           __ATOMIC_RELAXED, __HIP_MEMORY_SCOPE_AGENT);
    }
  }
}

// ---------------- regressor: pose = LeakyReLU(Y1 @ W1^T + b1) @ W2^T + b2 ----------------
__global__ __launch_bounds__(256) void regressor_kernel(
    const uint16_t* __restrict__ Y1, const uint16_t* __restrict__ W1b,
    const float* __restrict__ b1, const float* __restrict__ W2,
    const float* __restrict__ b2, float* __restrict__ pose)
{
  __shared__ float hdn[64 * 132];
  const int t = blockIdx.x;      // timestep
  const int tid = threadIdx.x;
  const int lane = tid & 63;
  const int wid = tid >> 6;
  const int n16 = lane & 15;
  const int kg = lane >> 4;

  const uint16_t* A  = Y1 + (size_t)(t + 1) * SLAB + (size_t)(wid * 16) * H_;
  const uint16_t* ap = A + (size_t)n16 * H_ + kg * 8;
  const uint16_t* bp = W1b + (size_t)n16 * H_ + kg * 8;

  f32x4 acc[8];
  #pragma unroll
  for (int i = 0; i < 8; ++i) acc[i] = (f32x4){0,0,0,0};

  #pragma unroll
  for (int ks = 0; ks < 24; ++ks) {
    bf16x8 av = *reinterpret_cast<const bf16x8*>(ap + ks * 32);
    #pragma unroll
    for (int nt = 0; nt < 8; ++nt) {
      bf16x8 bv = *reinterpret_cast<const bf16x8*>(bp + (size_t)nt * 16 * H_ + ks * 32);
      acc[nt] = mfma16(av, bv, acc[nt]);
    }
  }
  #pragma unroll
  for (int nt = 0; nt < 8; ++nt) {
    #pragma unroll
    for (int q = 0; q < 4; ++q) {
      int brow = wid * 16 + 4 * kg + q;
      int col  = nt * 16 + n16;
      float v = acc[nt][q] + b1[col];
      v = (v >= 0.0f) ? v : 0.1f * v;   // LeakyReLU(0.1)
      hdn[brow * 132 + col] = v;
    }
  }
  __syncthreads();
  for (int idx = tid; idx < 384; idx += 256) {
    int b = idx / 6, o = idx % 6;
    const float* w2r = W2 + o * 128;
    const float* hr  = &hdn[b * 132];
    float s = b2[o];
    #pragma unroll 4
    for (int c = 0; c < 128; ++c) s += hr[c] * w2r[c];
    pose[(size_t)b * (SEQ * 6) + (size_t)t * 6 + o] = s;
  }
}

extern "C" void kernel_launch(void* const* d_in, const int* in_sizes, int n_in,
                              void* d_out, int out_size, void* d_ws, size_t ws_size,
                              hipStream_t stream) {
  const float* fv  = (const float*)d_in[0];
  const float* fi  = (const float*)d_in[1];
  // d_in[2] = ts (unused by the reference)
  const float* Wih = (const float*)d_in[3];
  const float* Whh = (const float*)d_in[4];
  const float* bih = (const float*)d_in[5];
  const float* bhh = (const float*)d_in[6];
  const float* W1  = (const float*)d_in[7];
  const float* b1  = (const float*)d_in[8];
  const float* W2  = (const float*)d_in[9];
  const float* b2  = (const float*)d_in[10];
  float* out = (float*)d_out;   // [pose: 64*256*6][h_n: 2*64*768]

  char* ws = (char*)d_ws;
  size_t off = 0;
  uint8_t* fbytes = (uint8_t*)(ws + off);
  off += (size_t)257 * FB_ROUND;                 // 131,584 B
  off = (off + 255) & ~(size_t)255;
  uint16_t* Xbf = (uint16_t*)(ws + off); off += (size_t)SEQ * SLAB * 2;   // 25.2 MB
  uint16_t* Y0  = (uint16_t*)(ws + off); off += (size_t)257 * SLAB * 2;   // 25.3 MB
  uint16_t* Y1  = (uint16_t*)(ws + off); off += (size_t)257 * SLAB * 2;   // 25.3 MB
  uint16_t* W1b = (uint16_t*)(ws + off); off += (size_t)128 * H_ * 2;

  prep_kernel<<<2048, 256, 0, stream>>>(fv, fi, W1, Xbf, (int*)fbytes, W1b);
  gru_persist<<<192, 256, 0, stream>>>(Wih, Whh, bih, bhh, Xbf, Y0, Y1, fbytes, out + 98304);
  regressor_kernel<<<SEQ, 256, 0, stream>>>(Y1, W1b, b1, W2, b2, out);
}

// Round 12
// 2348.147 us; speedup vs baseline: 1.0689x; 1.0689x over previous
//
#include <hip/hip_runtime.h>
#include <stdint.h>

// PoseRNN: fused = cat(fv,fi) -> 2-layer GRU(768) -> Linear(768,128)+LeakyReLU(0.1) -> Linear(128,6)
// Persistent pipelined 2-layer GRU. Round-12: consolidate on the measured-best R9 skeleton
// (two barriers/round, dword flags, s_sleep spin, per-WG flag) with ONE restructure:
//   96 WGs x 512 threads (8 waves: 4 x-waves + 4 gh-waves, 16 batch rows each, full K).
//   - 2 waves/SIMD -> far-load + ds_read latency overlap (R9 ran 1 wave/SIMD, zero hiding)
//   - WG count halved -> half the flag-poll fabric traffic, fan-in stays 48
//   - hmast (running h) moved from LDS to 4 VGPRs/lane (same lane touches it every round)
//   - fast sigmoid/tanh via __expf (no libm branches) on the serial combine leg
// Visibility protocol unchanged (proven R7-R11): relaxed-agent write-through h stores,
// per-wave s_waitcnt drain + syncthreads, relaxed-agent L2-bypassing polls, zero fences.
// R10/R11 lessons kept OUT: no K/gate splitting (LDS reads not binding), no tight spin
// (fabric contention), no single-barrier restructure (neutral-to-negative).

typedef __attribute__((ext_vector_type(8))) short bf16x8;   // 8 bf16 in 4 VGPRs
typedef __attribute__((ext_vector_type(4))) short bf16x4;   // 8B
typedef __attribute__((ext_vector_type(4))) float f32x4;

#define H_   768
#define TH3  2304
#define BATCH 64
#define SEQ  256
#define SLAB (BATCH * H_)   /* 49152 elems, one timestep of h/y for all batches */
#define WROW 772            /* padded LDS row stride (ushorts) */
#define FL_STRIDE 128       /* ints per round: layer0 at +0, layer1 at +64 (48 used each) */

__device__ __forceinline__ uint16_t f2b(float f) {
  union { float f; uint32_t u; } v; v.f = f;
  uint32_t u = v.u;
  return (uint16_t)((u + 0x7FFFu + ((u >> 16) & 1u)) >> 16);  // RNE
}

__device__ __forceinline__ f32x4 mfma16(bf16x8 a, bf16x8 b, f32x4 c) {
  return __builtin_amdgcn_mfma_f32_16x16x32_bf16(a, b, c, 0, 0, 0);
}

__device__ __forceinline__ bf16x8 ldB(const uint16_t* p) {   // two ds_read_b64 (8B-aligned rows)
  bf16x4 lo = *reinterpret_cast<const bf16x4*>(p);
  bf16x4 hi = *reinterpret_cast<const bf16x4*>(p + 4);
  bf16x8 r;
  r[0] = lo[0]; r[1] = lo[1]; r[2] = lo[2]; r[3] = lo[3];
  r[4] = hi[0]; r[5] = hi[1]; r[6] = hi[2]; r[7] = hi[3];
  return r;
}

__device__ __forceinline__ void pollFlags48(const int* base, int lane) {
  const int* fp = base + (lane < 48 ? lane : 0);
  int spins = 0;
  for (;;) {
    int v = __hip_atomic_load(fp, __ATOMIC_RELAXED, __HIP_MEMORY_SCOPE_AGENT);
    if (lane >= 48) v = 1;
    if (__all(v != 0)) break;
    if (++spins > (1 << 16)) break;  // hang guard; break => absmax fail, not timeout
    __builtin_amdgcn_s_sleep(1);
  }
  __builtin_amdgcn_sched_barrier(0);  // nothing (esp. A-loads) may hoist above the poll
}

__device__ __forceinline__ float fsig(float x) {
  return 1.0f / (1.0f + __expf(-x));
}
__device__ __forceinline__ float ftanh(float x) {
  x = fminf(fmaxf(x, -15.0f), 15.0f);
  float e = __expf(2.0f * x);
  return (e - 1.0f) / (e + 1.0f);
}

// ---------------- prep: build time-major bf16 X, zero flags, bf16 W1 -------------
__global__ __launch_bounds__(256) void prep_kernel(
    const float* __restrict__ fv, const float* __restrict__ fi,
    const float* __restrict__ W1,
    uint16_t* __restrict__ Xbf, int* __restrict__ flags, uint16_t* __restrict__ W1b)
{
  const int NX = SEQ * SLAB;          // 12,582,912
  const int NC = 257 * FL_STRIDE;     // 32,896 flag ints
  const int NW = 128 * H_;
  const int total = NX + NC + NW;
  for (int idx = blockIdx.x * blockDim.x + threadIdx.x; idx < total;
       idx += gridDim.x * blockDim.x) {
    if (idx < NX) {
      int s = idx / SLAB;
      int rem = idx - s * SLAB;
      int b = rem / H_;
      int h = rem - b * H_;
      float val = (h < 512) ? fv[((size_t)b * SEQ + s) * 512 + h]
                            : fi[((size_t)b * SEQ + s) * 256 + (h - 512)];
      Xbf[idx] = f2b(val);
    } else if (idx < NX + NC) {
      flags[idx - NX] = 0;
    } else {
      int k = idx - NX - NC;
      W1b[k] = f2b(W1[k]);
    }
  }
}

// ---------------- persistent pipelined 2-layer GRU: 96 WGs x 512 threads ----------------
__global__ __launch_bounds__(512) void gru_persist(
    const float* __restrict__ Wih, const float* __restrict__ Whh,
    const float* __restrict__ bih, const float* __restrict__ bhh,
    const uint16_t* __restrict__ Xbf, uint16_t* __restrict__ Y0, uint16_t* __restrict__ Y1,
    int* __restrict__ flags, float* __restrict__ out_hn)
{
  __shared__ __attribute__((aligned(16))) uint16_t Wx[48 * WROW];  // 74,112 B
  __shared__ __attribute__((aligned(16))) uint16_t Wh[48 * WROW];  // 74,112 B
  __shared__ float ghbuf[64 * 48];                                 // 12,288 B
  __shared__ float bI[48];
  __shared__ float bH[48];                                         // total 160,896 B

  const int bid   = blockIdx.x;        // 0..95
  const int slice = bid % 48;          // hidden slice: units [slice*16, slice*16+16)
  const int layer = bid / 48;          // 0 or 1
  const int tid  = threadIdx.x;
  const int lane = tid & 63;
  const int wid  = tid >> 6;           // 8 waves
  const int isGh = wid >> 2;           // waves 0-3: x-GEMM+combine; waves 4-7: h-GEMM
  const int mblk = wid & 3;            // 16-batch block (0..3) within batch 64
  const int n16  = lane & 15;
  const int kg   = lane >> 4;

  // --- one-time: weight slices -> LDS bf16; rows ordered [r(16) z(16) n(16)] ---
  const float* wx_g = Wih + (size_t)layer * TH3 * H_;
  const float* wh_g = Whh + (size_t)layer * TH3 * H_;
  for (int idx = tid; idx < 48 * H_; idx += 512) {
    int lr = idx / H_;
    int c  = idx - lr * H_;
    int gate = lr >> 4, j = lr & 15;
    size_t grow = (size_t)(gate * H_ + slice * 16 + j);
    Wx[lr * WROW + c] = f2b(wx_g[grow * H_ + c]);
    Wh[lr * WROW + c] = f2b(wh_g[grow * H_ + c]);
  }
  if (tid < 48) {
    int gate = tid >> 4, j = tid & 15;
    bI[tid] = bih[layer * TH3 + gate * H_ + slice * 16 + j];
    bH[tid] = bhh[layer * TH3 + gate * H_ + slice * 16 + j];
  }
  __syncthreads();

  uint16_t* Yown = layer ? Y1 : Y0;
  const uint16_t* Wh_base = Wh + (size_t)n16 * WROW + kg * 8;
  const uint16_t* Wx_base = Wx + (size_t)n16 * WROW + kg * 8;

  f32x4 xac0 = {0,0,0,0}, xac1 = {0,0,0,0}, xac2 = {0,0,0,0};  // x-wave acc
  float hp[4] = {0.0f, 0.0f, 0.0f, 0.0f};                      // running h (x-waves), was hmast

  for (int i = 0; i <= 256; ++i) {
    const bool active = (layer == 0) ? (i < 256) : (i >= 1);
    const bool firstA = (layer == 0) ? (i == 0) : (i == 1);

    // ================= phase 1: GEMMs =================
    if (active) {
      if (isGh) {
        if (firstA) {
          // h0 == 0 -> gh == 0; no poll, no GEMM
          #pragma unroll
          for (int q = 0; q < 4; ++q) {
            int bi = mblk * 16 + 4 * kg + q;
            ghbuf[bi * 48 +      n16] = 0.0f;
            ghbuf[bi * 48 + 16 + n16] = 0.0f;
            ghbuf[bi * 48 + 32 + n16] = 0.0f;
          }
        } else {
          // h producers = own layer's 48 slices, round i-1
          pollFlags48(flags + (size_t)(i - 1) * FL_STRIDE + layer * 64, lane);
          const uint16_t* hs = (layer == 0) ? (Y0 + (size_t)i * SLAB)
                                            : (Y1 + (size_t)(i - 1) * SLAB);
          const uint16_t* ap = hs + (size_t)(mblk * 16 + n16) * H_ + kg * 8;
          f32x4 a0 = {0,0,0,0}, a1 = {0,0,0,0}, a2 = {0,0,0,0};
          #pragma unroll
          for (int ks = 0; ks < 24; ++ks) {
            bf16x8 av  = *reinterpret_cast<const bf16x8*>(ap + ks * 32);
            bf16x8 bv0 = ldB(Wh_base + ks * 32);
            bf16x8 bv1 = ldB(Wh_base + 16 * WROW + ks * 32);
            bf16x8 bv2 = ldB(Wh_base + 32 * WROW + ks * 32);
            a0 = mfma16(av, bv0, a0);
            a1 = mfma16(av, bv1, a1);
            a2 = mfma16(av, bv2, a2);
          }
          #pragma unroll
          for (int q = 0; q < 4; ++q) {
            int bi = mblk * 16 + 4 * kg + q;          // D row = 4*(lane>>4)+q
            ghbuf[bi * 48 +      n16] = a0[q];
            ghbuf[bi * 48 + 16 + n16] = a1[q];
            ghbuf[bi * 48 + 32 + n16] = a2[q];
          }
        }
      } else {
        // x input: layer0 reads Xbf[i] (static, no poll); layer1 reads Y0[i] (layer0, rnd i-1)
        if (layer == 1) pollFlags48(flags + (size_t)(i - 1) * FL_STRIDE, lane);
        const uint16_t* xs = (layer == 0) ? (Xbf + (size_t)i * SLAB)
                                          : (Y0 + (size_t)i * SLAB);
        const uint16_t* ap = xs + (size_t)(mblk * 16 + n16) * H_ + kg * 8;
        f32x4 a0 = {0,0,0,0}, a1 = {0,0,0,0}, a2 = {0,0,0,0};
        #pragma unroll
        for (int ks = 0; ks < 24; ++ks) {
          bf16x8 av  = *reinterpret_cast<const bf16x8*>(ap + ks * 32);
          bf16x8 bv0 = ldB(Wx_base + ks * 32);
          bf16x8 bv1 = ldB(Wx_base + 16 * WROW + ks * 32);
          bf16x8 bv2 = ldB(Wx_base + 32 * WROW + ks * 32);
          a0 = mfma16(av, bv0, a0);
          a1 = mfma16(av, bv1, a1);
          a2 = mfma16(av, bv2, a2);
        }
        xac0 = a0; xac1 = a1; xac2 = a2;
      }
    }
    __syncthreads();  // sync #1: ghbuf visible to combine waves

    // ================= phase 2: combine + store (x waves) =================
    if (active && !isGh) {
      uint16_t* dst = Yown + (size_t)((layer == 0) ? (i + 1) : i) * SLAB;
      const bool lastStep = (layer == 0) ? (i == 255) : (i == 256);
      #pragma unroll
      for (int q = 0; q < 4; ++q) {
        int bi = mblk * 16 + 4 * kg + q;
        float ghr = ghbuf[bi * 48 +      n16] + bH[n16];
        float ghz = ghbuf[bi * 48 + 16 + n16] + bH[16 + n16];
        float ghn = ghbuf[bi * 48 + 32 + n16] + bH[32 + n16];
        float gxr = xac0[q] + bI[n16];
        float gxz = xac1[q] + bI[16 + n16];
        float gxn = xac2[q] + bI[32 + n16];
        float rg = fsig(gxr + ghr);
        float zg = fsig(gxz + ghz);
        float ng = ftanh(gxn + rg * ghn);
        float hn2 = (1.0f - zg) * ng + zg * hp[q];
        hp[q] = hn2;
        // write-through (agent, relaxed) packed dword store: no dirty L2, no fences
        uint32_t lo = (uint32_t)f2b(hn2);
        uint32_t partner = (uint32_t)__shfl_xor((int)lo, 1, 64);  // col n16^1's bf16 bits
        if ((n16 & 1) == 0) {
          uint32_t pack = lo | (partner << 16);   // little-endian: col n16 low, n16+1 high
          uint32_t* p = (uint32_t*)(dst + (size_t)bi * H_ + slice * 16 + n16);
          __hip_atomic_store(p, pack, __ATOMIC_RELAXED, __HIP_MEMORY_SCOPE_AGENT);
        }
        if (lastStep)
          out_hn[(size_t)layer * SLAB + (size_t)bi * H_ + slice * 16 + n16] = hn2;
      }
      __builtin_amdgcn_s_waitcnt(0);      // drain THIS wave's h-stores before sync2
      __builtin_amdgcn_sched_barrier(0);
    }

    __syncthreads();  // sync #2: all x-waves' stores ACKed at coherence point

    if (i < 256 && tid == 0)
      __hip_atomic_store(&flags[(size_t)i * FL_STRIDE + layer * 64 + slice], 1,
                         __ATOMIC_RELAXED, __HIP_MEMORY_SCOPE_AGENT);
  }
}

// ---------------- regressor: pose = LeakyReLU(Y1 @ W1^T + b1) @ W2^T + b2 ----------------
__global__ __launch_bounds__(256) void regressor_kernel(
    const uint16_t* __restrict__ Y1, const uint16_t* __restrict__ W1b,
    const float* __restrict__ b1, const float* __restrict__ W2,
    const float* __restrict__ b2, float* __restrict__ pose)
{
  __shared__ float hdn[64 * 132];
  const int t = blockIdx.x;      // timestep
  const int tid = threadIdx.x;
  const int lane = tid & 63;
  const int wid = tid >> 6;
  const int n16 = lane & 15;
  const int kg = lane >> 4;

  const uint16_t* A  = Y1 + (size_t)(t + 1) * SLAB + (size_t)(wid * 16) * H_;
  const uint16_t* ap = A + (size_t)n16 * H_ + kg * 8;
  const uint16_t* bp = W1b + (size_t)n16 * H_ + kg * 8;

  f32x4 acc[8];
  #pragma unroll
  for (int i = 0; i < 8; ++i) acc[i] = (f32x4){0,0,0,0};

  #pragma unroll
  for (int ks = 0; ks < 24; ++ks) {
    bf16x8 av = *reinterpret_cast<const bf16x8*>(ap + ks * 32);
    #pragma unroll
    for (int nt = 0; nt < 8; ++nt) {
      bf16x8 bv = *reinterpret_cast<const bf16x8*>(bp + (size_t)nt * 16 * H_ + ks * 32);
      acc[nt] = mfma16(av, bv, acc[nt]);
    }
  }
  #pragma unroll
  for (int nt = 0; nt < 8; ++nt) {
    #pragma unroll
    for (int q = 0; q < 4; ++q) {
      int brow = wid * 16 + 4 * kg + q;
      int col  = nt * 16 + n16;
      float v = acc[nt][q] + b1[col];
      v = (v >= 0.0f) ? v : 0.1f * v;   // LeakyReLU(0.1)
      hdn[brow * 132 + col] = v;
    }
  }
  __syncthreads();
  for (int idx = tid; idx < 384; idx += 256) {
    int b = idx / 6, o = idx % 6;
    const float* w2r = W2 + o * 128;
    const float* hr  = &hdn[b * 132];
    float s = b2[o];
    #pragma unroll 4
    for (int c = 0; c < 128; ++c) s += hr[c] * w2r[c];
    pose[(size_t)b * (SEQ * 6) + (size_t)t * 6 + o] = s;
  }
}

extern "C" void kernel_launch(void* const* d_in, const int* in_sizes, int n_in,
                              void* d_out, int out_size, void* d_ws, size_t ws_size,
                              hipStream_t stream) {
  const float* fv  = (const float*)d_in[0];
  const float* fi  = (const float*)d_in[1];
  // d_in[2] = ts (unused by the reference)
  const float* Wih = (const float*)d_in[3];
  const float* Whh = (const float*)d_in[4];
  const float* bih = (const float*)d_in[5];
  const float* bhh = (const float*)d_in[6];
  const float* W1  = (const float*)d_in[7];
  const float* b1  = (const float*)d_in[8];
  const float* W2  = (const float*)d_in[9];
  const float* b2  = (const float*)d_in[10];
  float* out = (float*)d_out;   // [pose: 64*256*6][h_n: 2*64*768]

  char* ws = (char*)d_ws;
  size_t off = 0;
  int* flags = (int*)(ws + off);
  off += (size_t)257 * FL_STRIDE * sizeof(int);   // 131.6 KB
  off = (off + 255) & ~(size_t)255;
  uint16_t* Xbf = (uint16_t*)(ws + off); off += (size_t)SEQ * SLAB * 2;   // 25.2 MB
  uint16_t* Y0  = (uint16_t*)(ws + off); off += (size_t)257 * SLAB * 2;   // 25.3 MB
  uint16_t* Y1  = (uint16_t*)(ws + off); off += (size_t)257 * SLAB * 2;   // 25.3 MB
  uint16_t* W1b = (uint16_t*)(ws + off); off += (size_t)128 * H_ * 2;

  prep_kernel<<<2048, 256, 0, stream>>>(fv, fi, W1, Xbf, flags, W1b);
  gru_persist<<<96, 512, 0, stream>>>(Wih, Whh, bih, bhh, Xbf, Y0, Y1, flags, out + 98304);
  regressor_kernel<<<SEQ, 256, 0, stream>>>(Y1, W1b, b1, W2, b2, out);
}